// Round 5
// baseline (527.113 us; speedup 1.0000x reference)
//
#include <hip/hip_runtime.h>

typedef unsigned short u16;
typedef unsigned int   u32;
typedef __attribute__((ext_vector_type(4))) float f32x4;
typedef __attribute__((ext_vector_type(4))) u32   u32x4;
typedef __attribute__((ext_vector_type(4))) int   i32x4;
typedef __attribute__((ext_vector_type(8))) __bf16 bf16x8;

constexpr int NV   = 50000;   // vertices
constexpr int NE   = 25000;   // hyperedges
constexpr int NNZp = 400000;  // incidence pairs
constexpr int D    = 512;     // d_in == d_out
constexpr int MP2  = 25088;   // NE padded to 128 (196*128) -- GEMM rows
constexpr int NBE  = 25;      // scan blocks for E (1024 elems each)
constexpr int NBV  = 49;      // scan blocks for V
constexpr int BPS1 = 391;     // stage1 blocks per slice: ceil(NE/64)
constexpr int BPS2 = 1563;    // stage2 blocks per slice: ceil(NV/32)

static __device__ __forceinline__ u16 f2bf(float f) {
  u32 u = __float_as_uint(f);
  u32 r = (u + 0x7fffu + ((u >> 16) & 1u)) >> 16;  // RNE
  return (u16)r;
}
static __device__ __forceinline__ u32 pk2(float a, float b) {
  return (u32)f2bf(a) | ((u32)f2bf(b) << 16);
}

static __device__ __forceinline__ void gload_lds16(const u16* g, u16* l) {
  // async global->LDS, 16B per lane; LDS dest = wave-uniform base + lane*16
  __builtin_amdgcn_global_load_lds(
      (const __attribute__((address_space(1))) u32*)g,
      (__attribute__((address_space(3))) u32*)l, 16, 0, 0);
}

// ---------------- zero counters + degree histograms ----------------
__global__ void zero_kernel(int* cntE, int* cntV, int* dhistE, int* dhistV) {
  int i = blockIdx.x * 256 + threadIdx.x;
  if (i < NE) cntE[i] = 0;
  if (i < NV) cntV[i] = 0;
  if (i < 64) { dhistE[i] = 0; dhistV[i] = 0; }
}

// ---------------- histogram of incidence pairs ----------------
__global__ void hist_kernel(const int* __restrict__ vidx, const int* __restrict__ eidx,
                            int* cntE, int* cntV) {
  int i = blockIdx.x * 256 + threadIdx.x;
  if (i < NNZp) {
    atomicAdd(&cntE[eidx[i]], 1);
    atomicAdd(&cntV[vidx[i]], 1);
  }
}

// ---------------- degree histogram (64 buckets, LDS pre-aggregated) -------------------
__global__ __launch_bounds__(256) void deghist_kernel(
    const int* __restrict__ cntE, const int* __restrict__ cntV, int* dhistE, int* dhistV) {
  __shared__ int lhE[64], lhV[64];
  int t = threadIdx.x;
  if (t < 64) { lhE[t] = 0; lhV[t] = 0; }
  __syncthreads();
  int i = blockIdx.x * 256 + t;
  if (i < NE) atomicAdd(&lhE[min(cntE[i], 63)], 1);
  if (i < NV) atomicAdd(&lhV[min(cntV[i], 63)], 1);
  __syncthreads();
  if (t < 64) { if (lhE[t]) atomicAdd(&dhistE[t], lhE[t]); }
  else if (t < 128) { int u = t - 64; if (lhV[u]) atomicAdd(&dhistV[u], lhV[u]); }
}

// ---------------- scan pass 1: per-block (1024 elems) local exclusive scan -----------
__global__ __launch_bounds__(256) void scan1_kernel(
    const int* __restrict__ cntE, const int* __restrict__ cntV,
    int* offE, int* offV, int* blkSum) {
  const bool isE = blockIdx.x < NBE;
  const int* cnt = isE ? cntE : cntV;
  int* off = isE ? offE : offV;
  const int len = isE ? NE : NV;
  const int t = threadIdx.x;
  const int base = (isE ? blockIdx.x : blockIdx.x - NBE) * 1024 + t * 4;
  int4 c = {0, 0, 0, 0};
  if (base + 4 <= len) c = *(const int4*)(cnt + base);
  else {
    if (base + 0 < len) c.x = cnt[base + 0];
    if (base + 1 < len) c.y = cnt[base + 1];
    if (base + 2 < len) c.z = cnt[base + 2];
    if (base + 3 < len) c.w = cnt[base + 3];
  }
  int s = c.x + c.y + c.z + c.w;
  __shared__ int sm[256];
  sm[t] = s;
  __syncthreads();
  for (int d = 1; d < 256; d <<= 1) {
    int u = (t >= d) ? sm[t - d] : 0;
    __syncthreads();
    sm[t] += u;
    __syncthreads();
  }
  int ex = sm[t] - s;  // exclusive prefix within block
  int4 o;
  o.x = ex; o.y = o.x + c.x; o.z = o.y + c.y; o.w = o.z + c.z;
  if (base + 4 <= len) *(int4*)(off + base) = o;
  else {
    if (base + 0 < len) off[base + 0] = o.x;
    if (base + 1 < len) off[base + 1] = o.y;
    if (base + 2 < len) off[base + 2] = o.z;
    if (base + 3 < len) off[base + 3] = o.w;
  }
  if (t == 255) blkSum[blockIdx.x] = sm[255];
}

// ---------------- scan pass 2: wave-scan blkSums + degree hists (exclusive) ----------
__global__ void scan2_kernel(int* blkSum, const int* __restrict__ dhistE,
                             const int* __restrict__ dhistV, int* dcurE, int* dcurV) {
  int wv = threadIdx.x >> 6, lane = threadIdx.x & 63;
  const int* s; int* d; int len;
  if (wv == 0)      { s = blkSum;       d = blkSum;       len = NBE; }
  else if (wv == 1) { s = blkSum + NBE; d = blkSum + NBE; len = NBV; }
  else if (wv == 2) { s = dhistE;       d = dcurE;        len = 64;  }
  else              { s = dhistV;       d = dcurV;        len = 64;  }
  int v = (lane < len) ? s[lane] : 0;
  int incl = v;
#pragma unroll
  for (int dd = 1; dd < 64; dd <<= 1) {
    int u = __shfl_up(incl, dd, 64);
    if (lane >= dd) incl += u;
  }
  if (lane < len) d[lane] = incl - v;
}

// ---------------- scan pass 3: add block prefixes, materialize off & cur -------------
__global__ __launch_bounds__(256) void scan3_kernel(
    int* offE, int* offV, int* curE, int* curV, const int* __restrict__ blkSum) {
  const bool isE = blockIdx.x < NBE;
  int* off = isE ? offE : offV;
  int* cur = isE ? curE : curV;
  const int len = isE ? NE : NV;
  const int pref = blkSum[blockIdx.x];
  const int base = (isE ? blockIdx.x : blockIdx.x - NBE) * 1024 + threadIdx.x * 4;
  if (base + 4 <= len) {
    int4 o = *(int4*)(off + base);
    o.x += pref; o.y += pref; o.z += pref; o.w += pref;
    *(int4*)(off + base) = o;
    *(int4*)(cur + base) = o;
  } else {
    for (int q = 0; q < 4; q++)
      if (base + q < len) { int v = off[base + q] + pref; off[base + q] = v; cur[base + q] = v; }
  }
}

// ---------------- scatter pairs into CSR ----------------
__global__ void scatter_kernel(const int* __restrict__ vidx, const int* __restrict__ eidx,
                               int* curE, int* curV, int* csr_ev, int* csr_ve) {
  int i = blockIdx.x * 256 + threadIdx.x;
  if (i < NNZp) {
    int e = eidx[i], v = vidx[i];
    csr_ev[atomicAdd(&curE[e], 1)] = v;  // edge -> member vertices
    csr_ve[atomicAdd(&curV[v], 1)] = e;  // vertex -> incident edges
  }
}

// ---------------- counting-sort segments by degree; pack metadata as i32x4 -----------
// sE_meta[r] = {edge_id, off, cnt, 0}; sV_meta[r] = {vert_id, off, cnt, bits(degV)}.
__global__ __launch_bounds__(256) void degsort_kernel(
    const int* __restrict__ cntE, const int* __restrict__ offE,
    const int* __restrict__ cntV, const int* __restrict__ offV,
    const float* __restrict__ degV, int* dcurE, int* dcurV,
    i32x4* sE_meta, i32x4* sV_meta) {
  __shared__ int lhE[64], lhV[64], lbE[64], lbV[64];
  int t = threadIdx.x;
  if (t < 64) { lhE[t] = 0; lhV[t] = 0; }
  __syncthreads();
  int i = blockIdx.x * 256 + t;
  int bE = 0, rE = 0, bV = 0, rV = 0;
  if (i < NE) { bE = min(cntE[i], 63); rE = atomicAdd(&lhE[bE], 1); }
  if (i < NV) { bV = min(cntV[i], 63); rV = atomicAdd(&lhV[bV], 1); }
  __syncthreads();
  if (t < 64) { lbE[t] = lhE[t] ? atomicAdd(&dcurE[t], lhE[t]) : 0; }
  else if (t < 128) { int u = t - 64; lbV[u] = lhV[u] ? atomicAdd(&dcurV[u], lhV[u]) : 0; }
  __syncthreads();
  if (i < NE) {
    int r = lbE[bE] + rE;
    i32x4 m = { i, offE[i], cntE[i], 0 };
    sE_meta[r] = m;
  }
  if (i < NV) {
    int r = lbV[bV] + rV;
    i32x4 m = { i, offV[i], cntV[i], __float_as_int(degV[i]) };
    sV_meta[r] = m;
  }
}

// ---------------- fp32 -> bf16 convert -----------------------------------------------
// X -> Xb in SLICE-MAJOR layout [16][NV][32] (slice = 3.2 MB, fits one XCD's 4 MB L2).
// W -> Wb row-major. NT stores: no reuse within this kernel, keep L2 clean.
__global__ __launch_bounds__(256) void convert_kernel(
    const float* __restrict__ X, const float* __restrict__ W,
    u16* __restrict__ Xb, u16* __restrict__ Wb) {
  constexpr size_t NX = (size_t)NV * D;  // 25,600,000 (divisible by 8)
  size_t i = ((size_t)blockIdx.x * 256 + threadIdx.x) * 8;
  const float* src;
  u16* dst;
  if (i < NX) {
    int n = (int)(i >> 9);
    int col = (int)(i & 511);
    int t = col >> 5, w = col & 31;
    src = X + i;
    dst = Xb + (size_t)t * NV * 32 + (size_t)n * 32 + w;
  } else {
    src = W + (i - NX);
    dst = Wb + (i - NX);
  }
  f32x4 a = *(const f32x4*)src;
  f32x4 b = *(const f32x4*)(src + 4);
  u32x4 p = { pk2(a[0], a[1]), pk2(a[2], a[3]), pk2(b[0], b[1]), pk2(b[2], b[3]) };
  __builtin_nontemporal_store(p, (u32x4*)dst);
}

// ---------------- stage 1: vertex -> hyperedge ---------------------------------------
// Slice-pinned (16 x 32-col slices via bid&7 + phase), degree-sorted ranks, and
// LATENCY-AMORTIZED: per 16-member chunk, 16 independent idx loads (one wait), then
// 16 independent gathers (16-deep MLP), staggered unpack. csr/meta = NT streams
// (single use per slice); XeR = NT store. L2 holds only the 3.2 MB slice.
__global__ __launch_bounds__(256) void stage1_kernel(
    const u16* __restrict__ Xb, const i32x4* __restrict__ sE_meta,
    const int* __restrict__ csr_ev, u16* __restrict__ XeR) {
  const int wave = threadIdx.x >> 6;
  const int lane = threadIdx.x & 63;
  const int g    = lane >> 2;      // 0..15: segment slot
  const int c    = lane & 3;       // 4 lanes x 16B = 64B = 32 cols
  const int bid  = blockIdx.x;
  const int xcd  = bid & 7;
  const int tmp  = bid >> 3;                    // 0 .. 2*BPS1-1
  const int phase = (tmp >= BPS1) ? 1 : 0;
  const int eg    = tmp - phase * BPS1;
  const int t     = xcd + 8 * phase;            // slice 0..15
  const int rank  = eg * 64 + wave * 16 + g;
  const u16* base = Xb + (size_t)t * NV * 32;
  int e = 0, start = 0, cnt = 0;
  if (rank < NE) {
    i32x4 m = __builtin_nontemporal_load(sE_meta + rank);
    e = m.x; start = m.y; cnt = m.z;
  }
  float acc[8] = {};
  int b0 = 0;
  for (; b0 + 16 <= cnt; b0 += 16) {            // full chunks: no guards
    int idx[16];
#pragma unroll
    for (int p = 0; p < 16; p++) idx[p] = __builtin_nontemporal_load(csr_ev + start + b0 + p);
    u32x4 pk[16];
#pragma unroll
    for (int p = 0; p < 16; p++) pk[p] = *(const u32x4*)(base + (size_t)idx[p] * 32 + c * 8);
#pragma unroll
    for (int p = 0; p < 16; p++)
#pragma unroll
      for (int q = 0; q < 4; q++) {
        u32 u = pk[p][q];
        acc[2 * q]     += __uint_as_float(u << 16);
        acc[2 * q + 1] += __uint_as_float(u & 0xffff0000u);
      }
  }
  const int rem = cnt - b0;                     // 0..15, uniform per group
  if (rem > 0) {
    int idx[16];
#pragma unroll
    for (int p = 0; p < 16; p++) {
      int j = __builtin_nontemporal_load(csr_ev + start + b0 + p);  // <=60B overread: safe in ws
      idx[p] = (p < rem) ? j : 0;               // clamp to valid row 0
    }
    u32x4 pk[16];
#pragma unroll
    for (int p = 0; p < 16; p++) pk[p] = *(const u32x4*)(base + (size_t)idx[p] * 32 + c * 8);
#pragma unroll
    for (int p = 0; p < 16; p++)
      if (p < rem)
#pragma unroll
        for (int q = 0; q < 4; q++) {
          u32 u = pk[p][q];
          acc[2 * q]     += __uint_as_float(u << 16);
          acc[2 * q + 1] += __uint_as_float(u & 0xffff0000u);
        }
  }
  if (rank < NE) {
    u32x4 o = { pk2(acc[0], acc[1]), pk2(acc[2], acc[3]),
                pk2(acc[4], acc[5]), pk2(acc[6], acc[7]) };
    __builtin_nontemporal_store(o, (u32x4*)(XeR + (size_t)e * D + t * 32 + c * 8));
  }
}

// ---------------- GEMM: Xe2 = (XeR @ Wb^T) * (degE*Wdiag), slice-major output --------
// 128x128 tile, BK=32, 4 waves of 64x64, 16x16x32 MFMA (m97 structure).
__global__ __launch_bounds__(256) void gemm_kernel(const u16* __restrict__ A,
                                                   const u16* __restrict__ B,
                                                   const float* __restrict__ degE,
                                                   const float* __restrict__ Wdiag,
                                                   u16* __restrict__ C) {
  __shared__ u16 sA[128 * 32];
  __shared__ u16 sB[128 * 32];
  const int tid  = threadIdx.x;
  const int lane = tid & 63;
  const int wave = tid >> 6;
  const int bm = blockIdx.y * 128;
  const int bn = blockIdx.x * 128;
  const int wm = (wave >> 1) * 64;
  const int wn = (wave & 1) * 64;
  const int lr = lane & 15;
  const int lk = (lane >> 4) * 8;
  const int srow = lane >> 2;        // 0..15: row within 16-row staging stripe
  const int scol = (lane & 3) * 8;   // 0/8/16/24: k-elem offset (16B)

  f32x4 acc[4][4] = {};

  for (int kt = 0; kt < D; kt += 32) {
    __syncthreads();  // previous iteration's LDS readers done
#pragma unroll
    for (int c = 0; c < 2; c++) {
      const int ar = wave * 16 + c * 64;          // wave-uniform stripe base row
      gload_lds16(A + (size_t)(bm + ar + srow) * D + kt + scol, &sA[ar * 32]);
      gload_lds16(B + (size_t)(bn + ar + srow) * D + kt + scol, &sB[ar * 32]);
    }
    __syncthreads();  // drains vmcnt: staging complete

    bf16x8 af[4], bfr[4];
#pragma unroll
    for (int i = 0; i < 4; i++) af[i]  = *(const bf16x8*)&sA[(wm + i * 16 + lr) * 32 + lk];
#pragma unroll
    for (int j = 0; j < 4; j++) bfr[j] = *(const bf16x8*)&sB[(wn + j * 16 + lr) * 32 + lk];
#pragma unroll
    for (int i = 0; i < 4; i++)
#pragma unroll
      for (int j = 0; j < 4; j++)
        acc[i][j] = __builtin_amdgcn_mfma_f32_16x16x32_bf16(af[i], bfr[j], acc[i][j], 0, 0, 0);
  }

  // C/D layout (16x16): col = lane&15, row = (lane>>4)*4 + reg
  // Output slice-major [8][MP2][64]; scale rows by degE*Wdiag.
#pragma unroll
  for (int i = 0; i < 4; i++)
#pragma unroll
    for (int r = 0; r < 4; r++) {
      int row = bm + wm + i * 16 + (lane >> 4) * 4 + r;
      if (row < NE) {
        float se = degE[row] * Wdiag[row];
#pragma unroll
        for (int j = 0; j < 4; j++) {
          int col = bn + wn + lr + j * 16;
          int s = col >> 6, w = col & 63;
          __builtin_nontemporal_store(f2bf(acc[i][j][r] * se),
                                      C + (size_t)s * MP2 * 64 + (size_t)row * 64 + w);
        }
      }
    }
}

// ---------------- stage 2: hyperedge -> vertex ---------------------------------------
// Xe2 slice-major [8][MP2][64] (3.21 MB slice, pinned via bid&7). Wave = 8 groups x 8
// lanes, degree-sorted ranks, 16-member chunks with 16-deep independent gathers.
__global__ __launch_bounds__(256) void stage2_kernel(
    const u16* __restrict__ Xe2, const i32x4* __restrict__ sV_meta,
    const int* __restrict__ csr_ve, float* __restrict__ out) {
  const int wave = threadIdx.x >> 6;
  const int lane = threadIdx.x & 63;
  const int g    = lane >> 3;      // 0..7: segment slot
  const int c    = lane & 7;       // 8 lanes x 16B = 128B = 64 cols
  const int s    = blockIdx.x & 7;
  const int vg   = blockIdx.x >> 3;
  const int rank = vg * 32 + wave * 8 + g;
  const u16* base = Xe2 + (size_t)s * MP2 * 64;
  int v = 0, start = 0, cnt = 0;
  float dv = 0.f;
  if (rank < NV) {
    i32x4 m = __builtin_nontemporal_load(sV_meta + rank);
    v = m.x; start = m.y; cnt = m.z; dv = __int_as_float(m.w);
  }
  float acc[8] = {};
  int b0 = 0;
  for (; b0 + 16 <= cnt; b0 += 16) {            // full chunks: no guards
    int idx[16];
#pragma unroll
    for (int p = 0; p < 16; p++) idx[p] = __builtin_nontemporal_load(csr_ve + start + b0 + p);
    u32x4 pk[16];
#pragma unroll
    for (int p = 0; p < 16; p++) pk[p] = *(const u32x4*)(base + (size_t)idx[p] * 64 + c * 8);
#pragma unroll
    for (int p = 0; p < 16; p++)
#pragma unroll
      for (int q = 0; q < 4; q++) {
        u32 u = pk[p][q];
        acc[2 * q]     += __uint_as_float(u << 16);
        acc[2 * q + 1] += __uint_as_float(u & 0xffff0000u);
      }
  }
  const int rem = cnt - b0;                     // 0..15, uniform per group
  if (rem > 0) {
    int idx[16];
#pragma unroll
    for (int p = 0; p < 16; p++) {
      int j = __builtin_nontemporal_load(csr_ve + start + b0 + p);  // small overread: safe in ws
      idx[p] = (p < rem) ? j : 0;
    }
    u32x4 pk[16];
#pragma unroll
    for (int p = 0; p < 16; p++) pk[p] = *(const u32x4*)(base + (size_t)idx[p] * 64 + c * 8);
#pragma unroll
    for (int p = 0; p < 16; p++)
      if (p < rem)
#pragma unroll
        for (int q = 0; q < 4; q++) {
          u32 u = pk[p][q];
          acc[2 * q]     += __uint_as_float(u << 16);
          acc[2 * q + 1] += __uint_as_float(u & 0xffff0000u);
        }
  }
  if (rank < NV) {
    float* orow = out + (size_t)v * D + s * 64 + c * 8;
    f32x4 o0 = { acc[0] * dv, acc[1] * dv, acc[2] * dv, acc[3] * dv };
    f32x4 o1 = { acc[4] * dv, acc[5] * dv, acc[6] * dv, acc[7] * dv };
    __builtin_nontemporal_store(o0, (f32x4*)orow);
    __builtin_nontemporal_store(o1, (f32x4*)(orow + 4));
  }
}

extern "C" void kernel_launch(void* const* d_in, const int* in_sizes, int n_in,
                              void* d_out, int out_size, void* d_ws, size_t ws_size,
                              hipStream_t stream) {
  const float* X     = (const float*)d_in[0];
  const float* W     = (const float*)d_in[1];
  const float* degE  = (const float*)d_in[2];
  const float* degV  = (const float*)d_in[3];
  const float* Wdiag = (const float*)d_in[4];
  const int*   vidx  = (const int*)d_in[5];
  const int*   eidx  = (const int*)d_in[6];
  float* out = (float*)d_out;

  // workspace carve (all 256B aligned); total ~110 MB
  char* p = (char*)d_ws;
  auto take = [&](size_t bytes) { char* r = p; p += (bytes + 255) & ~(size_t)255; return r; };
  u16* Xb     = (u16*)take((size_t)NV * D * 2);    // bf16 X, slice-major [16][NV][32]
  u16* Wb     = (u16*)take((size_t)D * D * 2);     // bf16 W, row-major
  u16* XeR    = (u16*)take((size_t)MP2 * D * 2);   // bf16 raw edge sums, row-major
  u16* Xe2    = (u16*)take((size_t)MP2 * D * 2);   // bf16 projected+scaled, slice-major [8][MP2][64]
  int* cntE   = (int*)take((size_t)NE * 4);
  int* offE   = (int*)take((size_t)NE * 4);
  int* curE   = (int*)take((size_t)NE * 4);
  int* cntV   = (int*)take((size_t)NV * 4);
  int* offV   = (int*)take((size_t)NV * 4);
  int* curV   = (int*)take((size_t)NV * 4);
  int* csr_ev = (int*)take((size_t)NNZp * 4);
  int* csr_ve = (int*)take((size_t)NNZp * 4);
  int* blkSum = (int*)take((size_t)(NBE + NBV) * 4);
  int* dhistE = (int*)take(64 * 4);
  int* dhistV = (int*)take(64 * 4);
  int* dcurE  = (int*)take(64 * 4);
  int* dcurV  = (int*)take(64 * 4);
  i32x4* sE_meta = (i32x4*)take((size_t)NE * 16);
  i32x4* sV_meta = (i32x4*)take((size_t)NV * 16);

  constexpr size_t NCONV = ((size_t)NV * D + (size_t)D * D) / 8 / 256;  // 12628 exact
  constexpr int NSEG = (NV + 255) / 256;  // 196

  zero_kernel   <<<NSEG, 256, 0, stream>>>(cntE, cntV, dhistE, dhistV);
  hist_kernel   <<<(NNZp + 255) / 256, 256, 0, stream>>>(vidx, eidx, cntE, cntV);
  deghist_kernel<<<NSEG, 256, 0, stream>>>(cntE, cntV, dhistE, dhistV);
  scan1_kernel  <<<NBE + NBV, 256, 0, stream>>>(cntE, cntV, offE, offV, blkSum);
  scan2_kernel  <<<1, 256, 0, stream>>>(blkSum, dhistE, dhistV, dcurE, dcurV);
  scan3_kernel  <<<NBE + NBV, 256, 0, stream>>>(offE, offV, curE, curV, blkSum);
  scatter_kernel<<<(NNZp + 255) / 256, 256, 0, stream>>>(vidx, eidx, curE, curV, csr_ev, csr_ve);
  degsort_kernel<<<NSEG, 256, 0, stream>>>(cntE, offE, cntV, offV, degV, dcurE, dcurV,
                                           sE_meta, sV_meta);
  convert_kernel<<<NCONV, 256, 0, stream>>>(X, W, Xb, Wb);
  stage1_kernel <<<BPS1 * 16, 256, 0, stream>>>(Xb, sE_meta, csr_ev, XeR);
  gemm_kernel   <<<dim3(D / 128, MP2 / 128), 256, 0, stream>>>(XeR, Wb, degE, Wdiag, Xe2);
  stage2_kernel <<<BPS2 * 8, 256, 0, stream>>>(Xe2, sV_meta, csr_ve, out);
}

// Round 6
// 444.551 us; speedup vs baseline: 1.1857x; 1.1857x over previous
//
#include <hip/hip_runtime.h>

typedef unsigned short u16;
typedef unsigned int   u32;
typedef __attribute__((ext_vector_type(4))) float f32x4;
typedef __attribute__((ext_vector_type(4))) u32   u32x4;
typedef __attribute__((ext_vector_type(8))) __bf16 bf16x8;

constexpr int NV   = 50000;   // vertices
constexpr int NE   = 25000;   // hyperedges
constexpr int NNZp = 400000;  // incidence pairs
constexpr int D    = 512;     // d_in == d_out
constexpr int MP2  = 25088;   // NE padded to 128 (196*128) -- GEMM rows

static __device__ __forceinline__ u16 f2bf(float f) {
  u32 u = __float_as_uint(f);
  u32 r = (u + 0x7fffu + ((u >> 16) & 1u)) >> 16;  // RNE
  return (u16)r;
}
static __device__ __forceinline__ u32 pk2(float a, float b) {
  return (u32)f2bf(a) | ((u32)f2bf(b) << 16);
}

static __device__ __forceinline__ void gload_lds16(const u16* g, u16* l) {
  // async global->LDS, 16B per lane; LDS dest = wave-uniform base + lane*16
  __builtin_amdgcn_global_load_lds(
      (const __attribute__((address_space(1))) u32*)g,
      (__attribute__((address_space(3))) u32*)l, 16, 0, 0);
}

// ---------------- histogram of incidence pairs ----------------
__global__ void hist_kernel(const int* __restrict__ vidx, const int* __restrict__ eidx,
                            int* cntE, int* cntV) {
  int i = blockIdx.x * 256 + threadIdx.x;
  if (i < NNZp) {
    atomicAdd(&cntE[eidx[i]], 1);
    atomicAdd(&cntV[vidx[i]], 1);
  }
}

// ---------------- fused exclusive scan (single block, 1024 thr, shfl-based) ----------
// Scans cntE -> offE/curE then cntV -> offV/curV. 8 elems/thread/chunk, wave shfl
// scan + 16-wave LDS combine: 4 barriers per 8192-elem chunk, 11 chunks total.
__global__ __launch_bounds__(1024) void scan_kernel(
    const int* __restrict__ cntE, const int* __restrict__ cntV,
    int* offE, int* offV, int* curE, int* curV) {
  __shared__ int smw[16];
  __shared__ int carry;
  const int t = threadIdx.x, lane = t & 63, wv = t >> 6;
#pragma unroll
  for (int which = 0; which < 2; which++) {
    const int* cnt = which ? cntV : cntE;
    int* off = which ? offV : offE;
    int* cur = which ? curV : curE;
    const int len = which ? NV : NE;
    if (t == 0) carry = 0;
    __syncthreads();
    for (int base = 0; base < len; base += 8192) {
      int i = base + t * 8;
      int4 a = {0, 0, 0, 0}, b = {0, 0, 0, 0};
      if (i + 8 <= len) {
        a = *(const int4*)(cnt + i);
        b = *(const int4*)(cnt + i + 4);
      } else {
        int v[8];
        for (int q = 0; q < 8; q++) v[q] = (i + q < len) ? cnt[i + q] : 0;
        a.x = v[0]; a.y = v[1]; a.z = v[2]; a.w = v[3];
        b.x = v[4]; b.y = v[5]; b.z = v[6]; b.w = v[7];
      }
      int s = a.x + a.y + a.z + a.w + b.x + b.y + b.z + b.w;
      int incl = s;
#pragma unroll
      for (int d = 1; d < 64; d <<= 1) {
        int u = __shfl_up(incl, d, 64);
        if (lane >= d) incl += u;
      }
      if (lane == 63) smw[wv] = incl;
      __syncthreads();
      if (wv == 0) {
        int wval = (lane < 16) ? smw[lane] : 0;
        int winc = wval;
#pragma unroll
        for (int d = 1; d < 16; d <<= 1) {
          int u = __shfl_up(winc, d, 64);
          if (lane >= d) winc += u;
        }
        if (lane < 16) smw[lane] = winc - wval;  // exclusive wave prefix
      }
      __syncthreads();
      int ex = carry + smw[wv] + incl - s;
      int o0 = ex, o1 = o0 + a.x, o2 = o1 + a.y, o3 = o2 + a.z;
      int o4 = o3 + a.w, o5 = o4 + b.x, o6 = o5 + b.y, o7 = o6 + b.z;
      if (i + 8 <= len) {
        int4 oA = {o0, o1, o2, o3}, oB = {o4, o5, o6, o7};
        *(int4*)(off + i) = oA; *(int4*)(off + i + 4) = oB;
        *(int4*)(cur + i) = oA; *(int4*)(cur + i + 4) = oB;
      } else {
        int ov[8] = {o0, o1, o2, o3, o4, o5, o6, o7};
        for (int q = 0; q < 8; q++)
          if (i + q < len) { off[i + q] = ov[q]; cur[i + q] = ov[q]; }
      }
      __syncthreads();
      if (t == 1023) carry = ex + s;  // inclusive running total
      __syncthreads();
    }
  }
}

// ---------------- scatter pairs into CSR ----------------
__global__ void scatter_kernel(const int* __restrict__ vidx, const int* __restrict__ eidx,
                               int* curE, int* curV, int* csr_ev, int* csr_ve) {
  int i = blockIdx.x * 256 + threadIdx.x;
  if (i < NNZp) {
    int e = eidx[i], v = vidx[i];
    csr_ev[atomicAdd(&curE[e], 1)] = v;  // edge -> member vertices
    csr_ve[atomicAdd(&curV[v], 1)] = e;  // vertex -> incident edges
  }
}

// ---------------- fp32 -> bf16 convert -----------------------------------------------
// X -> Xb row-major [NV][D]; W -> Wb row-major. Pure streaming.
__global__ __launch_bounds__(256) void convert_kernel(
    const float* __restrict__ X, const float* __restrict__ W,
    u16* __restrict__ Xb, u16* __restrict__ Wb) {
  constexpr size_t NX = (size_t)NV * D;  // 25,600,000 (divisible by 8)
  size_t i = ((size_t)blockIdx.x * 256 + threadIdx.x) * 8;
  const float* src;
  u16* dst;
  if (i < NX) {
    src = X + i;
    dst = Xb + i;
  } else {
    src = W + (i - NX);
    dst = Wb + (i - NX);
  }
  f32x4 a = *(const f32x4*)src;
  f32x4 b = *(const f32x4*)(src + 4);
  u32x4 p = { pk2(a[0], a[1]), pk2(a[2], a[3]), pk2(b[0], b[1]), pk2(b[2], b[3]) };
  *(u32x4*)dst = p;
}

// ---------------- stage 1: vertex -> hyperedge (wave-per-edge, 8-deep prefetch) ------
// One wave owns one edge; 64 lanes x 16B = full 512-col bf16 row. Edge id is
// wave-uniform -> zero divergence; member indices loaded once (64 at a time) and
// broadcast via shfl; row loads issued in windows of 8 independent dwordx4.
__global__ __launch_bounds__(256) void stage1_kernel(
    const u16* __restrict__ Xb, const int* __restrict__ offE, const int* __restrict__ cntE,
    const int* __restrict__ csr_ev, u16* __restrict__ XeR) {
  const int wave = threadIdx.x >> 6;
  const int lane = threadIdx.x & 63;
  const int e = blockIdx.x * 4 + wave;
  if (e >= NE) return;
  const int start = offE[e];
  const int cnt   = cntE[e];
  float acc[8] = {};
  for (int b = 0; b < cnt; b += 64) {
    const int n = min(64, cnt - b);               // wave-uniform
    int idx = 0;
    if (lane < n) idx = csr_ev[start + b + lane]; // one coalesced index load
    int k0 = 0;
    for (; k0 + 8 <= n; k0 += 8) {                // full windows, uniform trip count
      u32x4 buf[8];
#pragma unroll
      for (int p = 0; p < 8; p++) {
        int v = __shfl(idx, k0 + p, 64);
        buf[p] = *(const u32x4*)(Xb + (size_t)v * D + lane * 8);
      }
#pragma unroll
      for (int p = 0; p < 8; p++) {
#pragma unroll
        for (int q = 0; q < 4; q++) {
          u32 u = buf[p][q];
          acc[2 * q]     += __uint_as_float(u << 16);
          acc[2 * q + 1] += __uint_as_float(u & 0xffff0000u);
        }
      }
    }
    const int rem = n - k0;                       // wave-uniform 0..7
    if (rem) {
      u32x4 buf[8];
#pragma unroll
      for (int p = 0; p < 8; p++) {
        if (p < rem) {
          int v = __shfl(idx, k0 + p, 64);
          buf[p] = *(const u32x4*)(Xb + (size_t)v * D + lane * 8);
        }
      }
#pragma unroll
      for (int p = 0; p < 8; p++) {
        if (p < rem) {
#pragma unroll
          for (int q = 0; q < 4; q++) {
            u32 u = buf[p][q];
            acc[2 * q]     += __uint_as_float(u << 16);
            acc[2 * q + 1] += __uint_as_float(u & 0xffff0000u);
          }
        }
      }
    }
  }
  u32x4 o = { pk2(acc[0], acc[1]), pk2(acc[2], acc[3]),
              pk2(acc[4], acc[5]), pk2(acc[6], acc[7]) };
  *(u32x4*)(XeR + (size_t)e * D + lane * 8) = o;
}

// ---------------- GEMM: Xe2 = (XeR @ Wb^T) * (degE*Wdiag), ROW-MAJOR output ----------
// 128x128 tile, BK=32, 4 waves of 64x64, 16x16x32 MFMA (m97 structure).
__global__ __launch_bounds__(256) void gemm_kernel(const u16* __restrict__ A,
                                                   const u16* __restrict__ B,
                                                   const float* __restrict__ degE,
                                                   const float* __restrict__ Wdiag,
                                                   u16* __restrict__ C) {
  __shared__ u16 sA[128 * 32];
  __shared__ u16 sB[128 * 32];
  const int tid  = threadIdx.x;
  const int lane = tid & 63;
  const int wave = tid >> 6;
  const int bm = blockIdx.y * 128;
  const int bn = blockIdx.x * 128;
  const int wm = (wave >> 1) * 64;
  const int wn = (wave & 1) * 64;
  const int lr = lane & 15;
  const int lk = (lane >> 4) * 8;
  const int srow = lane >> 2;        // 0..15: row within 16-row staging stripe
  const int scol = (lane & 3) * 8;   // 0/8/16/24: k-elem offset (16B)

  f32x4 acc[4][4] = {};

  for (int kt = 0; kt < D; kt += 32) {
    __syncthreads();  // previous iteration's LDS readers done
#pragma unroll
    for (int c = 0; c < 2; c++) {
      const int ar = wave * 16 + c * 64;          // wave-uniform stripe base row
      gload_lds16(A + (size_t)(bm + ar + srow) * D + kt + scol, &sA[ar * 32]);
      gload_lds16(B + (size_t)(bn + ar + srow) * D + kt + scol, &sB[ar * 32]);
    }
    __syncthreads();  // drains vmcnt: staging complete

    bf16x8 af[4], bfr[4];
#pragma unroll
    for (int i = 0; i < 4; i++) af[i]  = *(const bf16x8*)&sA[(wm + i * 16 + lr) * 32 + lk];
#pragma unroll
    for (int j = 0; j < 4; j++) bfr[j] = *(const bf16x8*)&sB[(wn + j * 16 + lr) * 32 + lk];
#pragma unroll
    for (int i = 0; i < 4; i++)
#pragma unroll
      for (int j = 0; j < 4; j++)
        acc[i][j] = __builtin_amdgcn_mfma_f32_16x16x32_bf16(af[i], bfr[j], acc[i][j], 0, 0, 0);
  }

  // C/D layout (16x16): col = lane&15, row = (lane>>4)*4 + reg
  // Output row-major [MP2][D] bf16; scale rows by degE*Wdiag.
#pragma unroll
  for (int i = 0; i < 4; i++)
#pragma unroll
    for (int r = 0; r < 4; r++) {
      int row = bm + wm + i * 16 + (lane >> 4) * 4 + r;
      if (row < NE) {
        float se = degE[row] * Wdiag[row];
#pragma unroll
        for (int j = 0; j < 4; j++) {
          int col = bn + wn + lr + j * 16;
          C[(size_t)row * D + col] = f2bf(acc[i][j][r] * se);
        }
      }
    }
}

// ---------------- stage 2: hyperedge -> vertex (wave-per-vertex, 8-deep prefetch) ----
// Same structure as stage1: one wave per vertex, full-row gathers from row-major Xe2,
// 8-deep load windows, uniform branches. Scale by degV, write f32 out row.
__global__ __launch_bounds__(256) void stage2_kernel(
    const u16* __restrict__ Xe2, const int* __restrict__ offV, const int* __restrict__ cntV,
    const int* __restrict__ csr_ve, const float* __restrict__ degV, float* __restrict__ out) {
  const int wave = threadIdx.x >> 6;
  const int lane = threadIdx.x & 63;
  const int v = blockIdx.x * 4 + wave;
  if (v >= NV) return;
  const int start = offV[v];
  const int cnt   = cntV[v];
  float acc[8] = {};
  for (int b = 0; b < cnt; b += 64) {
    const int n = min(64, cnt - b);               // wave-uniform
    int idx = 0;
    if (lane < n) idx = csr_ve[start + b + lane];
    int k0 = 0;
    for (; k0 + 8 <= n; k0 += 8) {
      u32x4 buf[8];
#pragma unroll
      for (int p = 0; p < 8; p++) {
        int e = __shfl(idx, k0 + p, 64);
        buf[p] = *(const u32x4*)(Xe2 + (size_t)e * D + lane * 8);
      }
#pragma unroll
      for (int p = 0; p < 8; p++) {
#pragma unroll
        for (int q = 0; q < 4; q++) {
          u32 u = buf[p][q];
          acc[2 * q]     += __uint_as_float(u << 16);
          acc[2 * q + 1] += __uint_as_float(u & 0xffff0000u);
        }
      }
    }
    const int rem = n - k0;                       // wave-uniform 0..7
    if (rem) {
      u32x4 buf[8];
#pragma unroll
      for (int p = 0; p < 8; p++) {
        if (p < rem) {
          int e = __shfl(idx, k0 + p, 64);
          buf[p] = *(const u32x4*)(Xe2 + (size_t)e * D + lane * 8);
        }
      }
#pragma unroll
      for (int p = 0; p < 8; p++) {
        if (p < rem) {
#pragma unroll
          for (int q = 0; q < 4; q++) {
            u32 u = buf[p][q];
            acc[2 * q]     += __uint_as_float(u << 16);
            acc[2 * q + 1] += __uint_as_float(u & 0xffff0000u);
          }
        }
      }
    }
  }
  const float sc = degV[v];
  float* orow = out + (size_t)v * D + lane * 8;
  f32x4 o0 = { acc[0] * sc, acc[1] * sc, acc[2] * sc, acc[3] * sc };
  f32x4 o1 = { acc[4] * sc, acc[5] * sc, acc[6] * sc, acc[7] * sc };
  *(f32x4*)orow = o0;
  *(f32x4*)(orow + 4) = o1;
}

extern "C" void kernel_launch(void* const* d_in, const int* in_sizes, int n_in,
                              void* d_out, int out_size, void* d_ws, size_t ws_size,
                              hipStream_t stream) {
  const float* X     = (const float*)d_in[0];
  const float* W     = (const float*)d_in[1];
  const float* degE  = (const float*)d_in[2];
  const float* degV  = (const float*)d_in[3];
  const float* Wdiag = (const float*)d_in[4];
  const int*   vidx  = (const int*)d_in[5];
  const int*   eidx  = (const int*)d_in[6];
  float* out = (float*)d_out;

  // workspace carve (all 256B aligned); total ~108 MB
  char* p = (char*)d_ws;
  auto take = [&](size_t bytes) { char* r = p; p += (bytes + 255) & ~(size_t)255; return r; };
  u16* Xb     = (u16*)take((size_t)NV * D * 2);    // bf16 X, row-major [NV][D]
  u16* Wb     = (u16*)take((size_t)D * D * 2);     // bf16 W, row-major
  u16* XeR    = (u16*)take((size_t)MP2 * D * 2);   // bf16 raw edge sums, row-major
  u16* Xe2    = (u16*)take((size_t)MP2 * D * 2);   // bf16 projected+scaled, row-major
  int* cntAll = (int*)take((size_t)(MP2 + NV) * 4); // cntE | cntV contiguous (one memset)
  int* cntE   = cntAll;
  int* cntV   = cntAll + MP2;
  int* offE   = (int*)take((size_t)NE * 4);
  int* offV   = (int*)take((size_t)NV * 4);
  int* curE   = (int*)take((size_t)NE * 4);
  int* curV   = (int*)take((size_t)NV * 4);
  int* csr_ev = (int*)take((size_t)NNZp * 4);
  int* csr_ve = (int*)take((size_t)NNZp * 4);

  constexpr size_t NCONV = ((size_t)NV * D + (size_t)D * D) / 8 / 256;  // 12628 exact

  hipMemsetAsync(cntAll, 0, (size_t)(MP2 + NV) * 4, stream);
  hist_kernel   <<<(NNZp + 255) / 256, 256, 0, stream>>>(vidx, eidx, cntE, cntV);
  scan_kernel   <<<1, 1024, 0, stream>>>(cntE, cntV, offE, offV, curE, curV);
  scatter_kernel<<<(NNZp + 255) / 256, 256, 0, stream>>>(vidx, eidx, curE, curV, csr_ev, csr_ve);
  convert_kernel<<<NCONV, 256, 0, stream>>>(X, W, Xb, Wb);
  stage1_kernel <<<NE / 4, 256, 0, stream>>>(Xb, offE, cntE, csr_ev, XeR);
  gemm_kernel   <<<dim3(D / 128, MP2 / 128), 256, 0, stream>>>(XeR, Wb, degE, Wdiag, Xe2);
  stage2_kernel <<<NV / 4, 256, 0, stream>>>(Xe2, offV, cntV, csr_ve, degV, out);
}

// Round 7
// 422.339 us; speedup vs baseline: 1.2481x; 1.0526x over previous
//
#include <hip/hip_runtime.h>

typedef unsigned short u16;
typedef unsigned int   u32;
typedef __attribute__((ext_vector_type(4))) float f32x4;
typedef __attribute__((ext_vector_type(4))) u32   u32x4;
typedef __attribute__((ext_vector_type(4))) int   i32x4;
typedef __attribute__((ext_vector_type(8))) __bf16 bf16x8;

constexpr int NV   = 50000;   // vertices
constexpr int NE   = 25000;   // hyperedges
constexpr int NNZp = 400000;  // incidence pairs
constexpr int D    = 512;     // d_in == d_out
constexpr int MP2  = 25088;   // NE padded to 128 (196*128) -- GEMM rows
constexpr int NBE  = 25;      // scan blocks for E (1024 elems each)
constexpr int NBV  = 49;      // scan blocks for V
constexpr int BPS1 = 391;     // stage1 blocks per slice: ceil(NE/64)
constexpr int BPS2 = 1563;    // stage2 blocks per slice: ceil(NV/32)

static __device__ __forceinline__ u16 f2bf(float f) {
  u32 u = __float_as_uint(f);
  u32 r = (u + 0x7fffu + ((u >> 16) & 1u)) >> 16;  // RNE
  return (u16)r;
}
static __device__ __forceinline__ u32 pk2(float a, float b) {
  return (u32)f2bf(a) | ((u32)f2bf(b) << 16);
}

static __device__ __forceinline__ void gload_lds16(const u16* g, u16* l) {
  // async global->LDS, 16B per lane; LDS dest = wave-uniform base + lane*16
  __builtin_amdgcn_global_load_lds(
      (const __attribute__((address_space(1))) u32*)g,
      (__attribute__((address_space(3))) u32*)l, 16, 0, 0);
}

// ---------------- zero counters + degree histograms ----------------
__global__ void zero_kernel(int* cntE, int* cntV, int* dhistE, int* dhistV) {
  int i = blockIdx.x * 256 + threadIdx.x;
  if (i < NE) cntE[i] = 0;
  if (i < NV) cntV[i] = 0;
  if (i < 64) { dhistE[i] = 0; dhistV[i] = 0; }
}

// ---------------- histogram of incidence pairs ----------------
__global__ void hist_kernel(const int* __restrict__ vidx, const int* __restrict__ eidx,
                            int* cntE, int* cntV) {
  int i = blockIdx.x * 256 + threadIdx.x;
  if (i < NNZp) {
    atomicAdd(&cntE[eidx[i]], 1);
    atomicAdd(&cntV[vidx[i]], 1);
  }
}

// ---------------- degree histogram (64 buckets, LDS pre-aggregated) -------------------
__global__ __launch_bounds__(256) void deghist_kernel(
    const int* __restrict__ cntE, const int* __restrict__ cntV, int* dhistE, int* dhistV) {
  __shared__ int lhE[64], lhV[64];
  int t = threadIdx.x;
  if (t < 64) { lhE[t] = 0; lhV[t] = 0; }
  __syncthreads();
  int i = blockIdx.x * 256 + t;
  if (i < NE) atomicAdd(&lhE[min(cntE[i], 63)], 1);
  if (i < NV) atomicAdd(&lhV[min(cntV[i], 63)], 1);
  __syncthreads();
  if (t < 64) { if (lhE[t]) atomicAdd(&dhistE[t], lhE[t]); }
  else if (t < 128) { int u = t - 64; if (lhV[u]) atomicAdd(&dhistV[u], lhV[u]); }
}

// ---------------- scan pass 1: per-block (1024 elems) local exclusive scan -----------
__global__ __launch_bounds__(256) void scan1_kernel(
    const int* __restrict__ cntE, const int* __restrict__ cntV,
    int* offE, int* offV, int* blkSum) {
  const bool isE = blockIdx.x < NBE;
  const int* cnt = isE ? cntE : cntV;
  int* off = isE ? offE : offV;
  const int len = isE ? NE : NV;
  const int t = threadIdx.x;
  const int base = (isE ? blockIdx.x : blockIdx.x - NBE) * 1024 + t * 4;
  int4 c = {0, 0, 0, 0};
  if (base + 4 <= len) c = *(const int4*)(cnt + base);
  else {
    if (base + 0 < len) c.x = cnt[base + 0];
    if (base + 1 < len) c.y = cnt[base + 1];
    if (base + 2 < len) c.z = cnt[base + 2];
    if (base + 3 < len) c.w = cnt[base + 3];
  }
  int s = c.x + c.y + c.z + c.w;
  __shared__ int sm[256];
  sm[t] = s;
  __syncthreads();
  for (int d = 1; d < 256; d <<= 1) {
    int u = (t >= d) ? sm[t - d] : 0;
    __syncthreads();
    sm[t] += u;
    __syncthreads();
  }
  int ex = sm[t] - s;  // exclusive prefix within block
  int4 o;
  o.x = ex; o.y = o.x + c.x; o.z = o.y + c.y; o.w = o.z + c.z;
  if (base + 4 <= len) *(int4*)(off + base) = o;
  else {
    if (base + 0 < len) off[base + 0] = o.x;
    if (base + 1 < len) off[base + 1] = o.y;
    if (base + 2 < len) off[base + 2] = o.z;
    if (base + 3 < len) off[base + 3] = o.w;
  }
  if (t == 255) blkSum[blockIdx.x] = sm[255];
}

// ---------------- scan pass 2: wave-scan blkSums + degree hists (exclusive) ----------
__global__ void scan2_kernel(int* blkSum, const int* __restrict__ dhistE,
                             const int* __restrict__ dhistV, int* dcurE, int* dcurV) {
  int wv = threadIdx.x >> 6, lane = threadIdx.x & 63;
  const int* s; int* d; int len;
  if (wv == 0)      { s = blkSum;       d = blkSum;       len = NBE; }
  else if (wv == 1) { s = blkSum + NBE; d = blkSum + NBE; len = NBV; }
  else if (wv == 2) { s = dhistE;       d = dcurE;        len = 64;  }
  else              { s = dhistV;       d = dcurV;        len = 64;  }
  int v = (lane < len) ? s[lane] : 0;
  int incl = v;
#pragma unroll
  for (int dd = 1; dd < 64; dd <<= 1) {
    int u = __shfl_up(incl, dd, 64);
    if (lane >= dd) incl += u;
  }
  if (lane < len) d[lane] = incl - v;
}

// ---------------- scan pass 3: add block prefixes, materialize off & cur -------------
__global__ __launch_bounds__(256) void scan3_kernel(
    int* offE, int* offV, int* curE, int* curV, const int* __restrict__ blkSum) {
  const bool isE = blockIdx.x < NBE;
  int* off = isE ? offE : offV;
  int* cur = isE ? curE : curV;
  const int len = isE ? NE : NV;
  const int pref = blkSum[blockIdx.x];
  const int base = (isE ? blockIdx.x : blockIdx.x - NBE) * 1024 + threadIdx.x * 4;
  if (base + 4 <= len) {
    int4 o = *(int4*)(off + base);
    o.x += pref; o.y += pref; o.z += pref; o.w += pref;
    *(int4*)(off + base) = o;
    *(int4*)(cur + base) = o;
  } else {
    for (int q = 0; q < 4; q++)
      if (base + q < len) { int v = off[base + q] + pref; off[base + q] = v; cur[base + q] = v; }
  }
}

// ---------------- scatter pairs into CSR ----------------
__global__ void scatter_kernel(const int* __restrict__ vidx, const int* __restrict__ eidx,
                               int* curE, int* curV, int* csr_ev, int* csr_ve) {
  int i = blockIdx.x * 256 + threadIdx.x;
  if (i < NNZp) {
    int e = eidx[i], v = vidx[i];
    csr_ev[atomicAdd(&curE[e], 1)] = v;  // edge -> member vertices
    csr_ve[atomicAdd(&curV[v], 1)] = e;  // vertex -> incident edges
  }
}

// ---------------- counting-sort segments by degree; pack metadata as i32x4 -----------
// sE_meta[r] = {edge_id, off, cnt, 0}; sV_meta[r] = {vert_id, off, cnt, bits(degV)}.
__global__ __launch_bounds__(256) void degsort_kernel(
    const int* __restrict__ cntE, const int* __restrict__ offE,
    const int* __restrict__ cntV, const int* __restrict__ offV,
    const float* __restrict__ degV, int* dcurE, int* dcurV,
    i32x4* sE_meta, i32x4* sV_meta) {
  __shared__ int lhE[64], lhV[64], lbE[64], lbV[64];
  int t = threadIdx.x;
  if (t < 64) { lhE[t] = 0; lhV[t] = 0; }
  __syncthreads();
  int i = blockIdx.x * 256 + t;
  int bE = 0, rE = 0, bV = 0, rV = 0;
  if (i < NE) { bE = min(cntE[i], 63); rE = atomicAdd(&lhE[bE], 1); }
  if (i < NV) { bV = min(cntV[i], 63); rV = atomicAdd(&lhV[bV], 1); }
  __syncthreads();
  if (t < 64) { lbE[t] = lhE[t] ? atomicAdd(&dcurE[t], lhE[t]) : 0; }
  else if (t < 128) { int u = t - 64; lbV[u] = lhV[u] ? atomicAdd(&dcurV[u], lhV[u]) : 0; }
  __syncthreads();
  if (i < NE) {
    int r = lbE[bE] + rE;
    i32x4 m = { i, offE[i], cntE[i], 0 };
    sE_meta[r] = m;
  }
  if (i < NV) {
    int r = lbV[bV] + rV;
    i32x4 m = { i, offV[i], cntV[i], __float_as_int(degV[i]) };
    sV_meta[r] = m;
  }
}

// ---------------- fp32 -> bf16 convert -----------------------------------------------
// X -> Xb in SLICE-MAJOR layout [16][NV][32] (slice = 3.2 MB, fits one XCD's 4 MB L2).
// W -> Wb row-major (GEMM B staging needs contiguous rows). Plain cached stores.
__global__ __launch_bounds__(256) void convert_kernel(
    const float* __restrict__ X, const float* __restrict__ W,
    u16* __restrict__ Xb, u16* __restrict__ Wb) {
  constexpr size_t NX = (size_t)NV * D;  // 25,600,000 (divisible by 8)
  size_t i = ((size_t)blockIdx.x * 256 + threadIdx.x) * 8;
  const float* src;
  u16* dst;
  if (i < NX) {
    int n = (int)(i >> 9);
    int col = (int)(i & 511);
    int t = col >> 5, w = col & 31;
    src = X + i;
    dst = Xb + (size_t)t * NV * 32 + (size_t)n * 32 + w;
  } else {
    src = W + (i - NX);
    dst = Wb + (i - NX);
  }
  f32x4 a = *(const f32x4*)src;
  f32x4 b = *(const f32x4*)(src + 4);
  u32x4 p = { pk2(a[0], a[1]), pk2(a[2], a[3]), pk2(b[0], b[1]), pk2(b[2], b[3]) };
  *(u32x4*)dst = p;
}

// ---------------- stage 1: vertex -> hyperedge ---------------------------------------
// Slice-pinned (16 x 32-col slices via bid&7 + phase), degree-SORTED ranks (uniform
// trip counts across a wave's 16 groups), and COALESCED CACHED idx loads: per 8-member
// window, the group's 4 lanes load 8 indices (two quads), shfl-broadcast, then 8
// independent 16B gathers in flight per lane. No nontemporal anywhere.
__global__ __launch_bounds__(256) void stage1_kernel(
    const u16* __restrict__ Xb, const i32x4* __restrict__ sE_meta,
    const int* __restrict__ csr_ev, u16* __restrict__ XeR) {
  const int wave = threadIdx.x >> 6;
  const int lane = threadIdx.x & 63;
  const int g    = lane >> 2;      // 0..15: segment slot
  const int c    = lane & 3;       // 4 lanes x 16B = 64B = 32 cols
  const int bid  = blockIdx.x;
  const int xcd  = bid & 7;
  const int tmp  = bid >> 3;                    // 0 .. 2*BPS1-1
  const int phase = (tmp >= BPS1) ? 1 : 0;
  const int eg    = tmp - phase * BPS1;
  const int t     = xcd + 8 * phase;            // slice 0..15
  const int rank  = eg * 64 + wave * 16 + g;
  const u16* base = Xb + (size_t)t * NV * 32;
  int e = 0, start = 0, cnt = 0;
  if (rank < NE) {
    i32x4 m = sE_meta[rank];
    e = m.x; start = m.y; cnt = m.z;
  }
  float acc[8] = {};
  for (int j0 = 0; j0 < cnt; j0 += 8) {
    int i0 = 0, i1 = 0;
    if (j0 + c < cnt)     i0 = csr_ev[start + j0 + c];
    if (j0 + 4 + c < cnt) i1 = csr_ev[start + j0 + 4 + c];
    u32x4 pk[8];
#pragma unroll
    for (int k = 0; k < 8; k++) {
      if (j0 + k < cnt) {
        int v = __shfl((k < 4) ? i0 : i1, (lane & ~3) | (k & 3), 64);
        pk[k] = *(const u32x4*)(base + (size_t)v * 32 + c * 8);
      }
    }
#pragma unroll
    for (int k = 0; k < 8; k++) {
      if (j0 + k < cnt) {
#pragma unroll
        for (int q = 0; q < 4; q++) {
          u32 u = pk[k][q];
          acc[2 * q]     += __uint_as_float(u << 16);
          acc[2 * q + 1] += __uint_as_float(u & 0xffff0000u);
        }
      }
    }
  }
  if (rank < NE) {
    u32x4 o = { pk2(acc[0], acc[1]), pk2(acc[2], acc[3]),
                pk2(acc[4], acc[5]), pk2(acc[6], acc[7]) };
    *(u32x4*)(XeR + (size_t)e * D + t * 32 + c * 8) = o;
  }
}

// ---------------- GEMM: Xe2 = (XeR @ Wb^T) * (degE*Wdiag), slice-major output --------
// 128x128 tile, BK=32, 4 waves of 64x64, 16x16x32 MFMA (m97 structure).
__global__ __launch_bounds__(256) void gemm_kernel(const u16* __restrict__ A,
                                                   const u16* __restrict__ B,
                                                   const float* __restrict__ degE,
                                                   const float* __restrict__ Wdiag,
                                                   u16* __restrict__ C) {
  __shared__ u16 sA[128 * 32];
  __shared__ u16 sB[128 * 32];
  const int tid  = threadIdx.x;
  const int lane = tid & 63;
  const int wave = tid >> 6;
  const int bm = blockIdx.y * 128;
  const int bn = blockIdx.x * 128;
  const int wm = (wave >> 1) * 64;
  const int wn = (wave & 1) * 64;
  const int lr = lane & 15;
  const int lk = (lane >> 4) * 8;
  const int srow = lane >> 2;        // 0..15: row within 16-row staging stripe
  const int scol = (lane & 3) * 8;   // 0/8/16/24: k-elem offset (16B)

  f32x4 acc[4][4] = {};

  for (int kt = 0; kt < D; kt += 32) {
    __syncthreads();  // previous iteration's LDS readers done
#pragma unroll
    for (int c = 0; c < 2; c++) {
      const int ar = wave * 16 + c * 64;          // wave-uniform stripe base row
      gload_lds16(A + (size_t)(bm + ar + srow) * D + kt + scol, &sA[ar * 32]);
      gload_lds16(B + (size_t)(bn + ar + srow) * D + kt + scol, &sB[ar * 32]);
    }
    __syncthreads();  // drains vmcnt: staging complete

    bf16x8 af[4], bfr[4];
#pragma unroll
    for (int i = 0; i < 4; i++) af[i]  = *(const bf16x8*)&sA[(wm + i * 16 + lr) * 32 + lk];
#pragma unroll
    for (int j = 0; j < 4; j++) bfr[j] = *(const bf16x8*)&sB[(wn + j * 16 + lr) * 32 + lk];
#pragma unroll
    for (int i = 0; i < 4; i++)
#pragma unroll
      for (int j = 0; j < 4; j++)
        acc[i][j] = __builtin_amdgcn_mfma_f32_16x16x32_bf16(af[i], bfr[j], acc[i][j], 0, 0, 0);
  }

  // C/D layout (16x16): col = lane&15, row = (lane>>4)*4 + reg
  // Output slice-major [8][MP2][64]; scale rows by degE*Wdiag.
#pragma unroll
  for (int i = 0; i < 4; i++)
#pragma unroll
    for (int r = 0; r < 4; r++) {
      int row = bm + wm + i * 16 + (lane >> 4) * 4 + r;
      if (row < NE) {
        float se = degE[row] * Wdiag[row];
#pragma unroll
        for (int j = 0; j < 4; j++) {
          int col = bn + wn + lr + j * 16;
          int s = col >> 6, w = col & 63;
          C[(size_t)s * MP2 * 64 + (size_t)row * 64 + w] = f2bf(acc[i][j][r] * se);
        }
      }
    }
}

// ---------------- stage 2: hyperedge -> vertex ---------------------------------------
// Xe2 slice-major [8][MP2][64] (3.21 MB slice, pinned via bid&7). Wave = 8 groups x 8
// lanes, degree-SORTED ranks, coalesced cached idx loads shfl-broadcast, 8-deep
// independent gathers per lane. No nontemporal anywhere.
__global__ __launch_bounds__(256) void stage2_kernel(
    const u16* __restrict__ Xe2, const i32x4* __restrict__ sV_meta,
    const int* __restrict__ csr_ve, float* __restrict__ out) {
  const int wave = threadIdx.x >> 6;
  const int lane = threadIdx.x & 63;
  const int g    = lane >> 3;      // 0..7: segment slot
  const int c    = lane & 7;       // 8 lanes x 16B = 128B = 64 cols
  const int s    = blockIdx.x & 7;
  const int vg   = blockIdx.x >> 3;
  const int rank = vg * 32 + wave * 8 + g;
  const u16* base = Xe2 + (size_t)s * MP2 * 64;
  int v = 0, start = 0, cnt = 0;
  float dv = 0.f;
  if (rank < NV) {
    i32x4 m = sV_meta[rank];
    v = m.x; start = m.y; cnt = m.z; dv = __int_as_float(m.w);
  }
  float acc[8] = {};
  for (int j0 = 0; j0 < cnt; j0 += 8) {
    int i0 = 0;
    if (j0 + c < cnt) i0 = csr_ve[start + j0 + c];  // 8 lanes load the group's 8 idx
    u32x4 pk[8];
#pragma unroll
    for (int k = 0; k < 8; k++) {
      if (j0 + k < cnt) {
        int e = __shfl(i0, (lane & ~7) | k, 64);
        pk[k] = *(const u32x4*)(base + (size_t)e * 64 + c * 8);
      }
    }
#pragma unroll
    for (int k = 0; k < 8; k++) {
      if (j0 + k < cnt) {
#pragma unroll
        for (int q = 0; q < 4; q++) {
          u32 u = pk[k][q];
          acc[2 * q]     += __uint_as_float(u << 16);
          acc[2 * q + 1] += __uint_as_float(u & 0xffff0000u);
        }
      }
    }
  }
  if (rank < NV) {
    float* orow = out + (size_t)v * D + s * 64 + c * 8;
    f32x4 o0 = { acc[0] * dv, acc[1] * dv, acc[2] * dv, acc[3] * dv };
    f32x4 o1 = { acc[4] * dv, acc[5] * dv, acc[6] * dv, acc[7] * dv };
    *(f32x4*)orow = o0;
    *(f32x4*)(orow + 4) = o1;
  }
}

extern "C" void kernel_launch(void* const* d_in, const int* in_sizes, int n_in,
                              void* d_out, int out_size, void* d_ws, size_t ws_size,
                              hipStream_t stream) {
  const float* X     = (const float*)d_in[0];
  const float* W     = (const float*)d_in[1];
  const float* degE  = (const float*)d_in[2];
  const float* degV  = (const float*)d_in[3];
  const float* Wdiag = (const float*)d_in[4];
  const int*   vidx  = (const int*)d_in[5];
  const int*   eidx  = (const int*)d_in[6];
  float* out = (float*)d_out;

  // workspace carve (all 256B aligned); total ~110 MB
  char* p = (char*)d_ws;
  auto take = [&](size_t bytes) { char* r = p; p += (bytes + 255) & ~(size_t)255; return r; };
  u16* Xb     = (u16*)take((size_t)NV * D * 2);    // bf16 X, slice-major [16][NV][32]
  u16* Wb     = (u16*)take((size_t)D * D * 2);     // bf16 W, row-major
  u16* XeR    = (u16*)take((size_t)MP2 * D * 2);   // bf16 raw edge sums, row-major
  u16* Xe2    = (u16*)take((size_t)MP2 * D * 2);   // bf16 projected+scaled, slice-major [8][MP2][64]
  int* cntE   = (int*)take((size_t)NE * 4);
  int* offE   = (int*)take((size_t)NE * 4);
  int* curE   = (int*)take((size_t)NE * 4);
  int* cntV   = (int*)take((size_t)NV * 4);
  int* offV   = (int*)take((size_t)NV * 4);
  int* curV   = (int*)take((size_t)NV * 4);
  int* csr_ev = (int*)take((size_t)NNZp * 4);
  int* csr_ve = (int*)take((size_t)NNZp * 4);
  int* blkSum = (int*)take((size_t)(NBE + NBV) * 4);
  int* dhistE = (int*)take(64 * 4);
  int* dhistV = (int*)take(64 * 4);
  int* dcurE  = (int*)take(64 * 4);
  int* dcurV  = (int*)take(64 * 4);
  i32x4* sE_meta = (i32x4*)take((size_t)NE * 16);
  i32x4* sV_meta = (i32x4*)take((size_t)NV * 16);

  constexpr size_t NCONV = ((size_t)NV * D + (size_t)D * D) / 8 / 256;  // 12628 exact
  constexpr int NSEG = (NV + 255) / 256;  // 196

  zero_kernel   <<<NSEG, 256, 0, stream>>>(cntE, cntV, dhistE, dhistV);
  hist_kernel   <<<(NNZp + 255) / 256, 256, 0, stream>>>(vidx, eidx, cntE, cntV);
  deghist_kernel<<<NSEG, 256, 0, stream>>>(cntE, cntV, dhistE, dhistV);
  scan1_kernel  <<<NBE + NBV, 256, 0, stream>>>(cntE, cntV, offE, offV, blkSum);
  scan2_kernel  <<<1, 256, 0, stream>>>(blkSum, dhistE, dhistV, dcurE, dcurV);
  scan3_kernel  <<<NBE + NBV, 256, 0, stream>>>(offE, offV, curE, curV, blkSum);
  scatter_kernel<<<(NNZp + 255) / 256, 256, 0, stream>>>(vidx, eidx, curE, curV, csr_ev, csr_ve);
  degsort_kernel<<<NSEG, 256, 0, stream>>>(cntE, offE, cntV, offV, degV, dcurE, dcurV,
                                           sE_meta, sV_meta);
  convert_kernel<<<NCONV, 256, 0, stream>>>(X, W, Xb, Wb);
  stage1_kernel <<<BPS1 * 16, 256, 0, stream>>>(Xb, sE_meta, csr_ev, XeR);
  gemm_kernel   <<<dim3(D / 128, MP2 / 128), 256, 0, stream>>>(XeR, Wb, degE, Wdiag, Xe2);
  stage2_kernel <<<BPS2 * 8, 256, 0, stream>>>(Xe2, sV_meta, csr_ve, out);
}